// Round 18
// baseline (269.898 us; speedup 1.0000x reference)
//
#include <hip/hip_runtime.h>
#include <math.h>
#include <stdint.h>

#define N_NODES 50000
#define N_EDGES 800000
#define IN_F 128
#define HID 64

#define NB    782                        // dst buckets of 64 nodes
#define CHUNK 4096
#define NCH   ((N_EDGES + CHUNK - 1) / CHUNK)   // 196
#define TOT   (NB * NCH)                 // 153272
#define SCAN_BLKS ((TOT + 255) / 256)    // 599  (< 1024 for scanB)

#define RB 16000                         // hist bins per range (62.5KB LDS)
#define NR 4                             // 4*16000 >= 50000
#define HP 64                            // slices per range -> 256 blocks

// ---------------------------------------------------------------------------
// src out-degree histogram: LDS-staged, coalesced global flush.
__global__ void hist_src_kernel(const int* __restrict__ src, int* __restrict__ cnt_src) {
    __shared__ int h[RB];
    int r = blockIdx.x / HP;             // range
    int p = blockIdx.x % HP;             // slice
    int t = threadIdx.x;
    for (int i = t; i < RB; i += 256) h[i] = 0;
    __syncthreads();
    int lo = r * RB, hi = lo + RB;
    int base = p * (N_EDGES / HP), lim = base + (N_EDGES / HP);   // 12500 exact
    for (int e = base + t; e < lim; e += 256) {
        int v = src[e];
        if (v >= lo && v < hi) atomicAdd(&h[v - lo], 1);
    }
    __syncthreads();
    for (int i = t; i < RB; i += 256) {
        int v = h[i];
        if (v && lo + i < N_NODES) atomicAdd(&cnt_src[lo + i], v);  // coalesced
    }
}

// ---------------------------------------------------------------------------
// per-chunk coarse histogram over dst buckets -> cnt2d[b][c]
__global__ void bucket_hist_kernel(const int* __restrict__ dst, int* __restrict__ cnt2d) {
    __shared__ int h[NB];
    int c = blockIdx.x, t = threadIdx.x;
    for (int i = t; i < NB; i += 256) h[i] = 0;
    __syncthreads();
    int base = c * CHUNK;
    int lim = base + CHUNK; if (lim > N_EDGES) lim = N_EDGES;
    for (int e = base + t; e < lim; e += 256) atomicAdd(&h[dst[e] >> 6], 1);
    __syncthreads();
    for (int i = t; i < NB; i += 256) cnt2d[i * NCH + c] = h[i];
}

// --- scan of cnt2d: A (per-block excl) + B (block offsets). The final add
// of bsum[idx>>8] is folded into the consumers (scanC eliminated). ----------
__global__ void scanA_kernel(int* __restrict__ a, int* __restrict__ bsum) {
    __shared__ int tmp[256];
    int t = threadIdx.x, gid = blockIdx.x * 256 + t;
    int v = (gid < TOT) ? a[gid] : 0;
    tmp[t] = v; __syncthreads();
    for (int off = 1; off < 256; off <<= 1) {
        int u = (t >= off) ? tmp[t - off] : 0;
        __syncthreads();
        tmp[t] += u;
        __syncthreads();
    }
    if (gid < TOT) a[gid] = tmp[t] - v;
    if (t == 255) bsum[blockIdx.x] = tmp[255];
}

__global__ void scanB_kernel(int* __restrict__ bsum) {
    __shared__ int tmp[1024];
    int t = threadIdx.x;
    int v = (t < SCAN_BLKS) ? bsum[t] : 0;
    tmp[t] = v; __syncthreads();
    for (int off = 1; off < 1024; off <<= 1) {
        int u = (t >= off) ? tmp[t - off] : 0;
        __syncthreads();
        tmp[t] += u;
        __syncthreads();
    }
    if (t < SCAN_BLKS) bsum[t] = tmp[t] - v;
}

// ---------------------------------------------------------------------------
// scatter edges into bucket order; cursors in LDS, bases = cnt2d + bsum.
// packed = (dst&63)<<16 | src   (src < 65536)
__global__ void bucket_scatter_kernel(const int* __restrict__ src, const int* __restrict__ dst,
                                      const int* __restrict__ cnt2d, const int* __restrict__ bsum,
                                      uint32_t* __restrict__ packed) {
    __shared__ int cur[NB];
    int c = blockIdx.x, t = threadIdx.x;
    for (int i = t; i < NB; i += 256) {
        int idx = i * NCH + c;
        cur[i] = cnt2d[idx] + bsum[idx >> 8];
    }
    __syncthreads();
    int base = c * CHUNK;
    int lim = base + CHUNK; if (lim > N_EDGES) lim = N_EDGES;
    for (int e = base + t; e < lim; e += 256) {
        int d = dst[e];
        int slot = atomicAdd(&cur[d >> 6], 1);
        packed[slot] = ((uint32_t)(d & 63) << 16) | (uint32_t)src[e];
    }
}

// ---------------------------------------------------------------------------
// within-bucket counting sort -> per-node CSR. 2-pass over the bucket's
// packed edges, LDS cursors. Also emits ndst. Bucket bounds = cnt2d + bsum.
__global__ void sort_bucket_kernel(const uint32_t* __restrict__ packed,
                                   const int* __restrict__ cnt2d,
                                   const int* __restrict__ bsum,
                                   int* __restrict__ sorted_src,
                                   int* __restrict__ node_offs,
                                   float* __restrict__ ndst) {
    __shared__ int hist[64], offs[64], cur[64];
    int b = blockIdx.x, t = threadIdx.x;
    if (t < 64) hist[t] = 0;
    __syncthreads();
    int i0 = b * NCH;
    int start = cnt2d[i0] + bsum[i0 >> 8];
    int end;
    if (b == NB - 1) end = N_EDGES;
    else { int i1 = (b + 1) * NCH; end = cnt2d[i1] + bsum[i1 >> 8]; }
    for (int e = start + t; e < end; e += 256) atomicAdd(&hist[packed[e] >> 16], 1);
    __syncthreads();
    if (t == 0) {
        int acc = 0;
        #pragma unroll
        for (int k = 0; k < 64; ++k) { offs[k] = acc; acc += hist[k]; }
    }
    __syncthreads();
    if (t < 64) {
        cur[t] = offs[t];
        int node = b * 64 + t;
        if (node < N_NODES) {
            node_offs[node] = start + offs[t];
            ndst[node] = 1.0f / sqrtf(fmaxf((float)hist[t], 1.0f));
        }
    }
    if (b == 0 && t == 0) node_offs[N_NODES] = N_EDGES;
    __syncthreads();
    for (int e = start + t; e < end; e += 256) {
        uint32_t pk = packed[e];
        int slot = start + atomicAdd(&cur[pk >> 16], 1);
        sorted_src[slot] = (int)(pk & 0xFFFF);
    }
}

// ---------------------------------------------------------------------------
// y1 = (x @ W1) * nsrc ; nsrc from cnt_src.  SPLIT-K x4:
// block = 64 rows x 4 waves; wave w owns k-chunk [32w,32w+32), each thread
// keeps the full acc[64] (same 64-chain ILP as R8) but 1/4 the k-work ->
// 3128 waves (~3/SIMD) instead of 784. Partials combined in fixed chunk
// order through LDS (wave0 writes, waves 1..3 add, barrier-separated ->
// deterministic). Epilogue: thread t stores bytes [t*64, t*64+64) of the
// block's 64x64 tile -> perfectly coalesced 16 KB contiguous store.
__global__ __launch_bounds__(256) void gemm1_kernel(
        const float* __restrict__ x, const float* __restrict__ W1,
        const int* __restrict__ cnt_src, float* __restrict__ nsrc,
        float* __restrict__ y1) {
    __shared__ float tile[64][65];
    int lane = threadIdx.x & 63;         // row within block
    int w    = threadIdx.x >> 6;         // k-chunk 0..3 (wave-uniform)
    int rowbase = blockIdx.x * 64;
    int row = rowbase + lane;

    float acc[HID];
    #pragma unroll
    for (int f = 0; f < HID; ++f) acc[f] = 0.0f;

    if (row < N_NODES) {
        float xk[32];
        const float4* xp = reinterpret_cast<const float4*>(x + (size_t)row * IN_F + w * 32);
        #pragma unroll
        for (int q = 0; q < 8; ++q) {
            float4 tq = xp[q];
            xk[4 * q + 0] = tq.x; xk[4 * q + 1] = tq.y;
            xk[4 * q + 2] = tq.z; xk[4 * q + 3] = tq.w;
        }
        #pragma unroll
        for (int k = 0; k < 32; ++k) {
            const float* wr = W1 + (size_t)(w * 32 + k) * HID;   // uniform -> s_load
            #pragma unroll
            for (int f = 0; f < HID; ++f) acc[f] = fmaf(xk[k], wr[f], acc[f]);
        }
    }

    // chunk-ordered combine: ((p0 + p1) + p2) + p3, deterministic.
    if (w == 0) {
        #pragma unroll
        for (int f = 0; f < HID; ++f) tile[lane][f] = acc[f];
    }
    __syncthreads();
    if (w == 1) {
        #pragma unroll
        for (int f = 0; f < HID; ++f) tile[lane][f] += acc[f];
    }
    __syncthreads();
    if (w == 2) {
        #pragma unroll
        for (int f = 0; f < HID; ++f) tile[lane][f] += acc[f];
    }
    __syncthreads();
    if (w == 3) {
        #pragma unroll
        for (int f = 0; f < HID; ++f) tile[lane][f] += acc[f];
    }
    __syncthreads();

    // epilogue: r = t/4 row, fq = t%4 feature-quarter -> contiguous stores
    int r  = threadIdx.x >> 2;
    int fq = threadIdx.x & 3;
    int orow = rowbase + r;
    if (orow < N_NODES) {
        float nn = 1.0f / sqrtf(fmaxf((float)cnt_src[orow], 1.0f));
        if (fq == 0) nsrc[orow] = nn;
        float4* yp = reinterpret_cast<float4*>(y1 + (size_t)orow * HID + fq * 16);
        #pragma unroll
        for (int q = 0; q < 4; ++q) {
            int f0 = fq * 16 + 4 * q;
            yp[q] = make_float4(tile[r][f0] * nn, tile[r][f0 + 1] * nn,
                                tile[r][f0 + 2] * nn, tile[r][f0 + 3] * nn);
        }
    }
}

// ---------------------------------------------------------------------------
// Layer-1 tail: wave per node, lane = feature, register accumulation.
// agg = sum y1[src]; h = relu(agg*ndst + b1)*drop; s = (h . W2) * nsrc
__global__ void gather1_kernel(const int* __restrict__ node_offs, const int* __restrict__ sorted_src,
                               const float* __restrict__ y1, const float* __restrict__ ndst,
                               const float* __restrict__ nsrc, const float* __restrict__ b1,
                               const float* __restrict__ drop, const float* __restrict__ W2,
                               float* __restrict__ s_out) {
    int lane = threadIdx.x & 63;
    int i = blockIdx.x * (blockDim.x >> 6) + (threadIdx.x >> 6);
    if (i >= N_NODES) return;

    int start = node_offs[i], end = node_offs[i + 1];
    float a0 = 0.0f, a1 = 0.0f, a2 = 0.0f, a3 = 0.0f;
    int j = start;
    for (; j + 4 <= end; j += 4) {
        int s0 = sorted_src[j + 0], s1 = sorted_src[j + 1];
        int s2 = sorted_src[j + 2], s3 = sorted_src[j + 3];
        a0 += y1[(size_t)s0 * HID + lane];
        a1 += y1[(size_t)s1 * HID + lane];
        a2 += y1[(size_t)s2 * HID + lane];
        a3 += y1[(size_t)s3 * HID + lane];
    }
    for (; j < end; ++j) a0 += y1[(size_t)sorted_src[j] * HID + lane];
    float acc = (a0 + a1) + (a2 + a3);

    float a = fmaxf(acc * ndst[i] + b1[lane], 0.0f) * drop[(size_t)i * HID + lane];
    float c = a * W2[lane];
    #pragma unroll
    for (int m = 32; m >= 1; m >>= 1) c += __shfl_xor(c, m, 64);
    if (lane == 0) s_out[i] = c * nsrc[i];
}

// Layer-2: wave per node, lane per edge, fused sigmoid.
__global__ void gather2_kernel(const int* __restrict__ node_offs, const int* __restrict__ sorted_src,
                               const float* __restrict__ s_arr, const float* __restrict__ ndst,
                               const float* __restrict__ b2, float* __restrict__ out) {
    int lane = threadIdx.x & 63;
    int i = blockIdx.x * (blockDim.x >> 6) + (threadIdx.x >> 6);
    if (i >= N_NODES) return;

    int start = node_offs[i], end = node_offs[i + 1];
    float c = 0.0f;
    for (int j = start + lane; j < end; j += 64) c += s_arr[sorted_src[j]];
    #pragma unroll
    for (int m = 32; m >= 1; m >>= 1) c += __shfl_xor(c, m, 64);
    if (lane == 0) {
        float v = c * ndst[i] + b2[0];
        out[i] = 1.0f / (1.0f + expf(-v));
    }
}

// ---------------------------------------------------------------------------
extern "C" void kernel_launch(void* const* d_in, const int* in_sizes, int n_in,
                              void* d_out, int out_size, void* d_ws, size_t ws_size,
                              hipStream_t stream) {
    const float* x    = (const float*)d_in[0];
    const float* W1   = (const float*)d_in[1];
    const float* b1   = (const float*)d_in[2];
    const float* W2   = (const float*)d_in[3];
    const float* b2   = (const float*)d_in[4];
    const int*   src  = (const int*)d_in[5];
    const int*   dst  = (const int*)d_in[6];
    const float* drop = (const float*)d_in[7];
    float* out = (float*)d_out;

    // workspace (~21 MB)
    float*    y1         = (float*)d_ws;                              // 64N
    uint32_t* packed     = (uint32_t*)(y1 + (size_t)HID * N_NODES);   // E
    int*      sorted_src = (int*)(packed + N_EDGES);                  // E
    int*      cnt2d      = sorted_src + N_EDGES;                      // TOT
    int*      bsum       = cnt2d + TOT;                               // 1024
    int*      cnt_src    = bsum + 1024;                               // N (zeroed)
    int*      node_offs  = cnt_src + N_NODES;                         // N+1
    float*    nsrc       = (float*)(node_offs + N_NODES + 1);         // N
    float*    ndst       = nsrc + N_NODES;                            // N
    float*    s_arr      = ndst + N_NODES;                            // N

    hipMemsetAsync(cnt_src, 0, (size_t)N_NODES * sizeof(int), stream);

    hist_src_kernel      <<<NR * HP, 256, 0, stream>>>(src, cnt_src);
    bucket_hist_kernel   <<<NCH, 256, 0, stream>>>(dst, cnt2d);
    scanA_kernel         <<<SCAN_BLKS, 256, 0, stream>>>(cnt2d, bsum);
    scanB_kernel         <<<1, 1024, 0, stream>>>(bsum);
    bucket_scatter_kernel<<<NCH, 256, 0, stream>>>(src, dst, cnt2d, bsum, packed);
    sort_bucket_kernel   <<<NB, 256, 0, stream>>>(packed, cnt2d, bsum, sorted_src, node_offs, ndst);
    gemm1_kernel         <<<NB, 256, 0, stream>>>(x, W1, cnt_src, nsrc, y1);
    gather1_kernel       <<<(N_NODES + 3) / 4, 256, 0, stream>>>(node_offs, sorted_src, y1, ndst, nsrc, b1, drop, W2, s_arr);
    gather2_kernel       <<<(N_NODES + 3) / 4, 256, 0, stream>>>(node_offs, sorted_src, s_arr, ndst, b2, out);
}